// Round 1
// 623.252 us; speedup vs baseline: 1.0923x; 1.0923x over previous
//
#include <hip/hip_runtime.h>
#include <math.h>

typedef __attribute__((ext_vector_type(8))) _Float16 f16x8;
typedef __attribute__((ext_vector_type(4))) _Float16 f16x4;
typedef __attribute__((ext_vector_type(4))) float f32x4;
typedef __attribute__((ext_vector_type(4))) short s16x4;

// ---------------------------------------------------------------------------
// Precision: GEMMs are split-fp16 (a = ah + al/2048) -> ~2^-22 rel.
// msc (the gathered message buffer) is int16 with a per-(row, 48-col-block)
// fp32 scale: abs err <= blockmax * 1.53e-5, ~1.5-2x the old fp16+fp8
// 2^-15 scheme. Anchor: bf16 msc (3.9e-3 rel) measured absmax 0.317 ->
// amplification ~81x; predicted absmax ~3-4e-3 vs threshold 1.9e-2.
//
// Round 12: msc 3 B/feature -> 2 B/feature. Aggregate is at 98% of the
// ~3.7 TB/s L2-fill fabric ceiling; gather traffic is compulsory
// (table x 8 XCDs), so only table bytes help: 28.8 MB -> 19.2 + 0.8 MB.
// Per-row-block max computed barrier-free in the GEMM epilogue via a
// 16-lane quad-group shfl_xor butterfly (a row's 48 cols live in one
// quad group). Decode in aggregate is 1 cvt + 1 fma per feature (VALU
// also drops vs f16+fp8 dual-chain decode).
// GEMM structure frozen from r10 (barrier-free, LDS-free, packed layout).
// Aggregation structure frozen from r7 (whole-row, wave-per-node).
// ---------------------------------------------------------------------------

// ------------------------- graph setup -------------------------------------
__global__ void scan1_kernel(const int* __restrict__ cnt, int M,
                             int* __restrict__ rowptr, int* __restrict__ bsum,
                             float* __restrict__ dinv) {
    __shared__ int s[256];
    int t = threadIdx.x;
    int i = blockIdx.x * 256 + t;
    int v = (i < M) ? cnt[i] : 0;
    s[t] = v; __syncthreads();
    for (int o = 1; o < 256; o <<= 1) {
        int x = (t >= o) ? s[t - o] : 0;
        __syncthreads();
        s[t] += x;
        __syncthreads();
    }
    if (i < M) {
        rowptr[i] = s[t] - v;
        dinv[i] = rsqrtf((float)v + 1.0f);  // deg = in-deg + self-loop
    }
    if (t == 255) bsum[blockIdx.x] = s[255];
}

__global__ void scan2_kernel(const int* __restrict__ bsum, int nb, int* __restrict__ boff) {
    __shared__ int s[256];
    int t = threadIdx.x;
    int v = (t < nb) ? bsum[t] : 0;
    s[t] = v; __syncthreads();
    for (int o = 1; o < 256; o <<= 1) {
        int x = (t >= o) ? s[t - o] : 0;
        __syncthreads();
        s[t] += x;
        __syncthreads();
    }
    if (t < nb) boff[t] = s[t] - v;
}

__global__ void scan3_kernel(int* __restrict__ rowptr, int M, int E, const int* __restrict__ boff) {
    int i = blockIdx.x * 256 + threadIdx.x;
    if (i < M) rowptr[i] += boff[blockIdx.x];
    if (i == M) rowptr[M] = E;
}

__global__ void fill_kernel(const int* __restrict__ src, const int* __restrict__ dst, int E,
                            const int* __restrict__ rowptr, int* __restrict__ cursor,
                            int* __restrict__ csr) {
    int i = blockIdx.x * blockDim.x + threadIdx.x;
    if (i < E) {
        int d = dst[i];
        int slot = atomicAdd(&cursor[d], 1);
        csr[rowptr[d] + slot] = src[i];
    }
}

// ---------------- fused prep: count + convert_x + pack_b --------------------
struct WSeg { const float* src; _Float16* dh; _Float16* dl; int K; int N; };
struct WSegs { WSeg s[8]; };

__global__ void prep_kernel(const int* __restrict__ dst, int E, int* __restrict__ cnt,
                            const float* __restrict__ x, _Float16* __restrict__ xp,
                            int M, int xchunks, WSegs segs,
                            int nCount, int nConv) {
    int b = blockIdx.x;
    if (b < nCount) {
        int i = b * 256 + threadIdx.x;
        if (i < E) atomicAdd(&cnt[dst[i]], 1);
        return;
    }
    b -= nCount;
    if (b < nConv) {
        // x -> block-packed split planes (4 slabs), one 16-B chunk per thread
        int g = b * 256 + threadIdx.x;
        if (g >= xchunks) return;
        int p = g & 7;
        int t1 = g >> 3;
        int r = t1 & 31;
        int t2 = t1 >> 5;
        int s = t2 & 3;
        int rb = t2 >> 2;
        int c = p ^ (r & 7);
        int node = rb * 32 + r;
        int k = s * 32 + (c & 3) * 8;
        f16x8 o = {};
        if (node < M) {
            const float* xr = x + (size_t)node * 128 + k;
#pragma unroll
            for (int j = 0; j < 8; ++j) {
                float v = xr[j];
                _Float16 hi = (_Float16)v;
                o[j] = (c < 4) ? hi : (_Float16)((v - (float)hi) * 2048.f);
            }
        }
        reinterpret_cast<f16x8*>(xp)[g] = o;
        return;
    }
    b -= nConv;
    // pack_b: frag-major WT planes, flat i = ((s*G+g)*64+l)*8+j
    WSeg sg = segs.s[b / 144];
    int i = (b % 144) * 256 + threadIdx.x;
    if (i >= sg.K * sg.N) return;
    int G = sg.N >> 4;
    int s = i / (G * 512);
    int r = i - s * (G * 512);
    int g = r >> 9;
    int r2 = r & 511;
    int l = r2 >> 3, j = r2 & 7;
    int n = g * 16 + (l & 15);
    int k = s * 32 + (l >> 4) * 8 + j;
    float w = sg.src[(size_t)k * sg.N + n];
    _Float16 hi = (_Float16)w;
    sg.dh[i] = hi;
    sg.dl[i] = (_Float16)((w - (float)hi) * 2048.f);
}

// ---------------------------------------------------------------------------
// Barrier-free LDS-free split-fp16 MFMA GEMM (r10 structure). 256 thr =
// 4 waves, 32 rows/block, wave w -> cols [w*48,+48) (NN=192). Direct
// sector-coalesced global loads; fully unrolled; no s_barrier.
// OM bit0: int16 + per-(row,48-block) scale msc out (Cq row-major 192,
//          Cs [row*4+wave]). rowscale applied before quantize; row-block
//          max via quad-group shfl_xor butterfly (16 lanes hold the 48
//          cols of one output row -> no LDS, no barrier).
// OM bit1: block-packed split out Cp.
// ---------------------------------------------------------------------------
template <int KK, int NN, int ACT, int OM>
__global__ __launch_bounds__(256, 4) void mfma_gemm(
    const _Float16* __restrict__ Ap,
    const _Float16* __restrict__ Bph, const _Float16* __restrict__ Bpl,
    const float* __restrict__ bias, const float* __restrict__ rowscale,
    short* __restrict__ Cq, float* __restrict__ Cs,
    _Float16* __restrict__ Cp, int M) {
    constexpr int NS = KK / 32;
    constexpr int G = NN / 16;
    constexpr int MT = 2;
    constexpr int NSO = NN / 32;

    const int tid = threadIdx.x;
    const int wave = tid >> 6, lane = tid & 63;
    const int quad = lane >> 4, l16 = lane & 15;
    const int n0 = wave * 48;
    const int g0 = n0 >> 4;
    const int row0 = blockIdx.x * 32;
    const _Float16* page0 = Ap + (size_t)blockIdx.x * NS * 2048;

    f32x4 acc[MT][3], acc2[MT][3];
#pragma unroll
    for (int mt = 0; mt < MT; ++mt)
#pragma unroll
        for (int nt = 0; nt < 3; ++nt) {
            acc[mt][nt] = (f32x4){0.f, 0.f, 0.f, 0.f};
            acc2[mt][nt] = (f32x4){0.f, 0.f, 0.f, 0.f};
        }

#pragma unroll
    for (int s = 0; s < NS; ++s) {
        const _Float16* pg = page0 + s * 2048;
        f16x8 ah[MT], al[MT];
#pragma unroll
        for (int mt = 0; mt < MT; ++mt) {
            int R = mt * 16 + l16;
            int ph = quad ^ (R & 7);
            ah[mt] = *reinterpret_cast<const f16x8*>(pg + R * 64 + ph * 8);
            al[mt] = *reinterpret_cast<const f16x8*>(pg + R * 64 + (ph ^ 4) * 8);
        }
        f16x8 bh[3], bl[3];
#pragma unroll
        for (int nt = 0; nt < 3; ++nt) {
            size_t o = ((size_t)(s * G + g0 + nt) * 64 + lane) * 8;
            bh[nt] = *reinterpret_cast<const f16x8*>(Bph + o);
            bl[nt] = *reinterpret_cast<const f16x8*>(Bpl + o);
        }
#pragma unroll
        for (int mt = 0; mt < MT; ++mt)
#pragma unroll
            for (int nt = 0; nt < 3; ++nt) {
                acc[mt][nt] = __builtin_amdgcn_mfma_f32_16x16x32_f16(ah[mt], bh[nt], acc[mt][nt], 0, 0, 0);
                acc2[mt][nt] = __builtin_amdgcn_mfma_f32_16x16x32_f16(ah[mt], bl[nt], acc2[mt][nt], 0, 0, 0);
                acc2[mt][nt] = __builtin_amdgcn_mfma_f32_16x16x32_f16(al[mt], bh[nt], acc2[mt][nt], 0, 0, 0);
            }
    }

    // epilogue: C/D layout col=lane&15, row=quad*4+reg
    float bv[3];
#pragma unroll
    for (int nt = 0; nt < 3; ++nt) bv[nt] = bias ? bias[n0 + nt * 16 + l16] : 0.f;
#pragma unroll
    for (int mt = 0; mt < MT; ++mt)
#pragma unroll
        for (int i = 0; i < 4; ++i) {
            int row = row0 + mt * 16 + quad * 4 + i;
            if (row < M) {
                float rs = rowscale ? rowscale[row] : 1.f;
                float v[3];
#pragma unroll
                for (int nt = 0; nt < 3; ++nt) {
                    float t = acc[mt][nt][i] + acc2[mt][nt][i] * (1.f / 2048.f) + bv[nt];
                    if (ACT == 1) t = fmaxf(t, 0.f);
                    v[nt] = t * rs;
                }
                if (OM & 1) {
                    // row-block max over this wave's 48 cols of this row:
                    // the 16 lanes of this quad group hold them (3 regs each).
                    float m = fmaxf(fmaxf(fabsf(v[0]), fabsf(v[1])), fabsf(v[2]));
#pragma unroll
                    for (int d = 1; d < 16; d <<= 1) m = fmaxf(m, __shfl_xor(m, d));
                    float inv = (m > 0.f) ? 32767.f / m : 0.f;
#pragma unroll
                    for (int nt = 0; nt < 3; ++nt) {
                        int col = n0 + nt * 16 + l16;
                        Cq[(size_t)row * NN + col] = (short)rintf(v[nt] * inv);
                    }
                    if (l16 == 0) Cs[row * 4 + wave] = m * (1.f / 32767.f);
                }
                if (OM & 2) {
#pragma unroll
                    for (int nt = 0; nt < 3; ++nt) {
                        int col = n0 + nt * 16 + l16;
                        float vv = v[nt];
                        _Float16 hi = (_Float16)vv;
                        _Float16 lo = (_Float16)((vv - (float)hi) * 2048.f);
                        int r = row & 31;
                        int os = col >> 5, oc = (col >> 3) & 3, j = col & 7;
                        size_t base = ((size_t)((row >> 5) * NSO + os) * 32 + r) * 64;
                        int ph2 = oc ^ (r & 7);
                        Cp[base + ph2 * 8 + j] = hi;
                        Cp[base + (ph2 ^ 4) * 8 + j] = lo;
                    }
                }
            }
        }
}

// ---------------------------------------------------------------------------
// int16 whole-row aggregation (r7 structure, r12 encoding). One wave per
// node, lanes 0..47: per edge load s16x4 (8 B) + per-48-block scale (4 B);
// decode = 1 cvt + 1 fma per feature, two independent accumulator chains.
// h = h + relu(dinv[n]*sum + B); h block-packed split-fp16.
// ---------------------------------------------------------------------------
__global__ __launch_bounds__(256) void aggregate_kernel(
    const short* __restrict__ mscq, const float* __restrict__ mscs,
    const int* __restrict__ csr, const int* __restrict__ rowptr,
    const float* __restrict__ dinv, const float* __restrict__ bias,
    _Float16* __restrict__ h, int M) {
    int wid = (blockIdx.x * 256 + threadIdx.x) >> 6;
    int lane = threadIdx.x & 63;
    if (wid >= M || lane >= 48) return;
    const int soff = lane / 12;  // 48-col-block index for features lane*4..+4

    // self-loop term
    s16x4 q0 = *reinterpret_cast<const s16x4*>(mscq + (size_t)wid * 192 + lane * 4);
    float f0v = mscs[wid * 4 + soff];
    float4 a0, a1;
    a0.x = (float)q0[0] * f0v; a0.y = (float)q0[1] * f0v;
    a0.z = (float)q0[2] * f0v; a0.w = (float)q0[3] * f0v;
    a1 = make_float4(0.f, 0.f, 0.f, 0.f);

    int beg = rowptr[wid], end = rowptr[wid + 1];
    int e = beg;
    for (; e + 1 < end; e += 2) {
        int sa = csr[e], sb = csr[e + 1];
        s16x4 qa = *reinterpret_cast<const s16x4*>(mscq + (size_t)sa * 192 + lane * 4);
        float fa = mscs[sa * 4 + soff];
        s16x4 qb = *reinterpret_cast<const s16x4*>(mscq + (size_t)sb * 192 + lane * 4);
        float fb = mscs[sb * 4 + soff];
        a0.x = fmaf((float)qa[0], fa, a0.x);
        a0.y = fmaf((float)qa[1], fa, a0.y);
        a0.z = fmaf((float)qa[2], fa, a0.z);
        a0.w = fmaf((float)qa[3], fa, a0.w);
        a1.x = fmaf((float)qb[0], fb, a1.x);
        a1.y = fmaf((float)qb[1], fb, a1.y);
        a1.z = fmaf((float)qb[2], fb, a1.z);
        a1.w = fmaf((float)qb[3], fb, a1.w);
    }
    if (e < end) {
        int sa = csr[e];
        s16x4 qa = *reinterpret_cast<const s16x4*>(mscq + (size_t)sa * 192 + lane * 4);
        float fa = mscs[sa * 4 + soff];
        a0.x = fmaf((float)qa[0], fa, a0.x);
        a0.y = fmaf((float)qa[1], fa, a0.y);
        a0.z = fmaf((float)qa[2], fa, a0.z);
        a0.w = fmaf((float)qa[3], fa, a0.w);
    }
    float4 a;
    a.x = a0.x + a1.x;
    a.y = a0.y + a1.y;
    a.z = a0.z + a1.z;
    a.w = a0.w + a1.w;

    float dn = dinv[wid];
    float4 b = reinterpret_cast<const float4*>(bias)[lane];

    // packed-h granule for features f0 = lane*4 .. +4
    int f0 = lane * 4;
    int s = f0 >> 5, c = (f0 >> 3) & 3, jh = (f0 >> 2) & 1;
    int r = wid & 31;
    size_t pbase = ((size_t)((wid >> 5) * 6 + s) * 32 + r) * 64;
    int ph = c ^ (r & 7);
    f16x4* hp = reinterpret_cast<f16x4*>(h + pbase + ph * 8 + jh * 4);
    f16x4* lp = reinterpret_cast<f16x4*>(h + pbase + (ph ^ 4) * 8 + jh * 4);
    f16x4 hh = *hp, hl = *lp;
    float4 hv;
    hv.x = (float)hh[0] + (float)hl[0] * (1.f / 2048.f) + fmaxf(a.x * dn + b.x, 0.f);
    hv.y = (float)hh[1] + (float)hl[1] * (1.f / 2048.f) + fmaxf(a.y * dn + b.y, 0.f);
    hv.z = (float)hh[2] + (float)hl[2] * (1.f / 2048.f) + fmaxf(a.z * dn + b.z, 0.f);
    hv.w = (float)hh[3] + (float)hl[3] * (1.f / 2048.f) + fmaxf(a.w * dn + b.w, 0.f);
    f16x4 nh = {(_Float16)hv.x, (_Float16)hv.y, (_Float16)hv.z, (_Float16)hv.w};
    f16x4 nl = {(_Float16)((hv.x - (float)nh[0]) * 2048.f),
                (_Float16)((hv.y - (float)nh[1]) * 2048.f),
                (_Float16)((hv.z - (float)nh[2]) * 2048.f),
                (_Float16)((hv.w - (float)nh[3]) * 2048.f)};
    *hp = nh;
    *lp = nl;
}

// ---------------------------------------------------------------------------
// Fused tail (r10): p2 = relu(p1@Wp2+b), r = relu(h@Wr1+b) direct-load
// MFMA; then pos = p2·Wp3+bp3, rad = sigmoid(r·Wr2+br2),
// out = pos/(|pos|+1e-8)*rad. 32 rows/block.
// ---------------------------------------------------------------------------
__global__ __launch_bounds__(256, 2) void tail_kernel(
    const _Float16* __restrict__ p1p, const _Float16* __restrict__ hp_,
    const _Float16* __restrict__ W2h, const _Float16* __restrict__ W2l,
    const _Float16* __restrict__ Wrh, const _Float16* __restrict__ Wrl,
    const float* __restrict__ bp2, const float* __restrict__ br1,
    const float* __restrict__ Wp3, const float* __restrict__ bp3,
    const float* __restrict__ Wr2, const float* __restrict__ br2,
    float* __restrict__ out, int M) {
    __shared__ float p2t[32 * 96];
    __shared__ float rbt[32 * 96];
    const int tid = threadIdx.x;
    const int wave = tid >> 6, lane = tid & 63;
    const int quad = lane >> 4, l16 = lane & 15;
    const int m0 = (wave >> 1) * 16;
    const int n0 = (wave & 1) * 48;
    const int g0 = n0 >> 4;  // G = 6
    const int row0 = blockIdx.x * 32;

    f32x4 aP[3], aP2[3], aR[3], aR2[3];
#pragma unroll
    for (int nt = 0; nt < 3; ++nt) {
        aP[nt] = (f32x4){0.f, 0.f, 0.f, 0.f};
        aP2[nt] = aP[nt]; aR[nt] = aP[nt]; aR2[nt] = aP[nt];
    }

#pragma unroll
    for (int s = 0; s < 6; ++s) {
        const _Float16* pgP = p1p + ((size_t)blockIdx.x * 6 + s) * 2048;
        const _Float16* pgH = hp_ + ((size_t)blockIdx.x * 6 + s) * 2048;
        int R = m0 + l16;
        int ph = quad ^ (R & 7);
        f16x8 p1h = *reinterpret_cast<const f16x8*>(pgP + R * 64 + ph * 8);
        f16x8 p1l = *reinterpret_cast<const f16x8*>(pgP + R * 64 + (ph ^ 4) * 8);
        f16x8 hh = *reinterpret_cast<const f16x8*>(pgH + R * 64 + ph * 8);
        f16x8 hl = *reinterpret_cast<const f16x8*>(pgH + R * 64 + (ph ^ 4) * 8);
        f16x8 b2h[3], b2l[3], brh[3], brl[3];
#pragma unroll
        for (int nt = 0; nt < 3; ++nt) {
            size_t o = ((size_t)(s * 6 + g0 + nt) * 64 + lane) * 8;
            b2h[nt] = *reinterpret_cast<const f16x8*>(W2h + o);
            b2l[nt] = *reinterpret_cast<const f16x8*>(W2l + o);
            brh[nt] = *reinterpret_cast<const f16x8*>(Wrh + o);
            brl[nt] = *reinterpret_cast<const f16x8*>(Wrl + o);
        }
#pragma unroll
        for (int nt = 0; nt < 3; ++nt) {
            aP[nt] = __builtin_amdgcn_mfma_f32_16x16x32_f16(p1h, b2h[nt], aP[nt], 0, 0, 0);
            aP2[nt] = __builtin_amdgcn_mfma_f32_16x16x32_f16(p1h, b2l[nt], aP2[nt], 0, 0, 0);
            aP2[nt] = __builtin_amdgcn_mfma_f32_16x16x32_f16(p1l, b2h[nt], aP2[nt], 0, 0, 0);
            aR[nt] = __builtin_amdgcn_mfma_f32_16x16x32_f16(hh, brh[nt], aR[nt], 0, 0, 0);
            aR2[nt] = __builtin_amdgcn_mfma_f32_16x16x32_f16(hh, brl[nt], aR2[nt], 0, 0, 0);
            aR2[nt] = __builtin_amdgcn_mfma_f32_16x16x32_f16(hl, brh[nt], aR2[nt], 0, 0, 0);
        }
    }

#pragma unroll
    for (int i = 0; i < 4; ++i) {
        int row = m0 + quad * 4 + i;  // 0..31
#pragma unroll
        for (int nt = 0; nt < 3; ++nt) {
            int col = n0 + nt * 16 + l16;
            float v2 = aP[nt][i] + aP2[nt][i] * (1.f / 2048.f) + bp2[col];
            float vr = aR[nt][i] + aR2[nt][i] * (1.f / 2048.f) + br1[col];
            p2t[row * 96 + col] = fmaxf(v2, 0.f);
            rbt[row * 96 + col] = fmaxf(vr, 0.f);
        }
    }
    __syncthreads();

    if (tid < 32) {
        int row = row0 + tid;
        if (row < M) {
            float a0 = 0.f, a1 = 0.f, rr = 0.f;
            const float* p = p2t + tid * 96;
            const float* r = rbt + tid * 96;
#pragma unroll
            for (int j = 0; j < 96; ++j) {
                a0 += p[j] * Wp3[j * 2 + 0];
                a1 += p[j] * Wp3[j * 2 + 1];
                rr += r[j] * Wr2[j];
            }
            a0 += bp3[0];
            a1 += bp3[1];
            rr += br2[0];
            float radius = 1.f / (1.f + expf(-rr));
            float nrm = sqrtf(a0 * a0 + a1 * a1) + 1e-8f;
            float sc = radius / nrm;
            out[(size_t)row * 2 + 0] = a0 * sc;
            out[(size_t)row * 2 + 1] = a1 * sc;
        }
    }
}

extern "C" void kernel_launch(void* const* d_in, const int* in_sizes, int n_in,
                              void* d_out, int out_size, void* d_ws, size_t ws_size,
                              hipStream_t stream) {
    const float* x     = (const float*)d_in[0];
    const int*   ei    = (const int*)d_in[1];
    const float* Wp    = (const float*)d_in[2];
    const float* bp    = (const float*)d_in[3];
    const float* convW = (const float*)d_in[4];
    const float* convB = (const float*)d_in[5];
    const float* Wp1   = (const float*)d_in[6];
    const float* bp1   = (const float*)d_in[7];
    const float* Wp2   = (const float*)d_in[8];
    const float* bp2   = (const float*)d_in[9];
    const float* Wp3   = (const float*)d_in[10];
    const float* bp3   = (const float*)d_in[11];
    const float* Wr1   = (const float*)d_in[12];
    const float* br1   = (const float*)d_in[13];
    const float* Wr2   = (const float*)d_in[14];
    const float* br2   = (const float*)d_in[15];
    float* out = (float*)d_out;

    const int M = in_sizes[0] / 128;  // 50000
    const int E = in_sizes[1] / 2;    // 800000
    const int* srcI = ei;
    const int* dstI = ei + E;
    const int RBp = (M + 31) / 32;    // 1563 32-row pages / GEMM blocks
    const int Mr  = RBp * 32;

    char* w = (char*)d_ws;
    size_t off = 0;
    auto alloc = [&](size_t b) { size_t o = off; off += (b + 255) & ~(size_t)255; return o; };
    // msc region also hosts p1 packed later (38.4 MB >= 19.2+0.8 int16+scale)
    char*     mscreg = w + alloc((size_t)RBp * 6 * 4096);
    _Float16* hpk  = (_Float16*)(w + alloc((size_t)RBp * 6 * 4096)); // h packed
    _Float16* xpk  = (_Float16*)(w + alloc((size_t)RBp * 4 * 4096)); // x packed
    _Float16* WpPh  = (_Float16*)(w + alloc((size_t)128 * 192 * 2));
    _Float16* WpPl  = (_Float16*)(w + alloc((size_t)128 * 192 * 2));
    _Float16* cWPh  = (_Float16*)(w + alloc((size_t)4 * 192 * 192 * 2));
    _Float16* cWPl  = (_Float16*)(w + alloc((size_t)4 * 192 * 192 * 2));
    _Float16* Wp1Ph = (_Float16*)(w + alloc((size_t)192 * 192 * 2));
    _Float16* Wp1Pl = (_Float16*)(w + alloc((size_t)192 * 192 * 2));
    _Float16* Wp2Ph = (_Float16*)(w + alloc((size_t)192 * 96 * 2));
    _Float16* Wp2Pl = (_Float16*)(w + alloc((size_t)192 * 96 * 2));
    _Float16* Wr1Ph = (_Float16*)(w + alloc((size_t)192 * 96 * 2));
    _Float16* Wr1Pl = (_Float16*)(w + alloc((size_t)192 * 96 * 2));
    int*      cnt    = (int*)(w + alloc((size_t)M * 4));
    int*      cursor = (int*)(w + alloc((size_t)M * 4));
    float*    dinv   = (float*)(w + alloc((size_t)M * 4));
    int*      rowptr = (int*)(w + alloc((size_t)(M + 1) * 4));
    int*      csr    = (int*)(w + alloc((size_t)(E + 64) * 4));
    int*      bsum   = (int*)(w + alloc(256 * 4));
    int*      boff   = (int*)(w + alloc(256 * 4));

    short*    mscq = (short*)mscreg;                                   // 19.2 MB
    float*    mscs = (float*)(mscreg + (size_t)Mr * 192 * 2);          // 0.8 MB
    _Float16* p1pk = (_Float16*)mscreg;  // alias: msc dead after last aggregate

    hipMemsetAsync(cnt, 0, (size_t)((char*)cursor - (char*)cnt) + (size_t)M * 4, stream);

    // fused prep: count + convert_x + pack_b
    const int xchunks = RBp * 4 * 256;
    const int nCount = (E + 255) / 256;
    const int nConv  = (xchunks + 255) / 256;
    WSegs segs;
    segs.s[0] = {Wp, WpPh, WpPl, 128, 192};
    segs.s[1] = {convW + 0 * 192 * 192, cWPh + 0 * 192 * 192, cWPl + 0 * 192 * 192, 192, 192};
    segs.s[2] = {convW + 1 * 192 * 192, cWPh + 1 * 192 * 192, cWPl + 1 * 192 * 192, 192, 192};
    segs.s[3] = {convW + 2 * 192 * 192, cWPh + 2 * 192 * 192, cWPl + 2 * 192 * 192, 192, 192};
    segs.s[4] = {convW + 3 * 192 * 192, cWPh + 3 * 192 * 192, cWPl + 3 * 192 * 192, 192, 192};
    segs.s[5] = {Wp1, Wp1Ph, Wp1Pl, 192, 192};
    segs.s[6] = {Wp2, Wp2Ph, Wp2Pl, 192, 96};
    segs.s[7] = {Wr1, Wr1Ph, Wr1Pl, 192, 96};
    prep_kernel<<<nCount + nConv + 8 * 144, 256, 0, stream>>>(
        dstI, E, cnt, x, xpk, M, xchunks, segs, nCount, nConv);

    int nb = (M + 255) / 256;
    scan1_kernel<<<nb, 256, 0, stream>>>(cnt, M, rowptr, bsum, dinv);
    scan2_kernel<<<1, 256, 0, stream>>>(bsum, nb, boff);
    scan3_kernel<<<(M + 256) / 256, 256, 0, stream>>>(rowptr, M, E, boff);
    fill_kernel<<<(E + 255) / 256, 256, 0, stream>>>(srcI, dstI, E, rowptr, cursor, csr);

    // h = x @ Wp + bp -> packed planes
    mfma_gemm<128, 192, 0, 2><<<RBp, 256, 0, stream>>>(
        xpk, WpPh, WpPl, bp, nullptr, nullptr, nullptr, hpk, M);
    // 4 GCN layers: msc = (h@W)*dinv -> int16+scale planes; whole-row aggregate
    for (int i = 0; i < 4; i++) {
        mfma_gemm<192, 192, 0, 1><<<RBp, 256, 0, stream>>>(
            hpk, cWPh + (size_t)i * 192 * 192, cWPl + (size_t)i * 192 * 192,
            nullptr, dinv, mscq, mscs, nullptr, M);
        aggregate_kernel<<<(M + 3) / 4, 256, 0, stream>>>(
            mscq, mscs, csr, rowptr, dinv, convB + (size_t)i * 192, hpk, M);
    }
    // p1 = relu(h @ Wp1 + bp1) -> packed (aliases msc region)
    mfma_gemm<192, 192, 1, 2><<<RBp, 256, 0, stream>>>(
        hpk, Wp1Ph, Wp1Pl, bp1, nullptr, nullptr, nullptr, p1pk, M);
    // fused p2/r GEMMs + finalize
    tail_kernel<<<RBp, 256, 0, stream>>>(
        p1pk, hpk, Wp2Ph, Wp2Pl, Wr1Ph, Wr1Pl, bp2, br1,
        Wp3, bp3, Wr2, br2, out, M);
}